// Round 4
// baseline (394.436 us; speedup 1.0000x reference)
//
#include <hip/hip_runtime.h>
#include <hip/hip_bf16.h>

#define T_TOK 4096
#define DIM   768
#define FF    3072
#define NE    8

typedef __attribute__((ext_vector_type(8))) short bf16x8;
typedef __attribute__((ext_vector_type(4))) short bf16x4;
typedef __attribute__((ext_vector_type(4))) float f32x4;
typedef __attribute__((ext_vector_type(2))) float f32x2;

typedef __attribute__((address_space(1))) void gvoid_t;
typedef __attribute__((address_space(3))) void lvoid_t;

__device__ __forceinline__ void g2l16(const void* g, void* l) {
    // async global->LDS, 16B per lane; LDS dest must be wave-uniform base
    __builtin_amdgcn_global_load_lds((gvoid_t*)(void*)g, (lvoid_t*)l, 16, 0, 0);
}

// wait vmcnt(0), ignore lgkmcnt/expcnt: gfx9 enc vm[3:0]|exp[6:4]|lgkm[11:8]|vm[15:14]
#define WAIT_VM0() __builtin_amdgcn_s_waitcnt(0x0F70)
#define RAW_BARRIER() asm volatile("s_barrier" ::: "memory")

__device__ __forceinline__ unsigned short f2bf(float f) {
    union { float f; unsigned int u; } v; v.f = f;
    unsigned int u = v.u;
    u += 0x7FFFu + ((u >> 16) & 1u);   // round-to-nearest-even
    return (unsigned short)(u >> 16);
}

__device__ __forceinline__ bf16x8 pack8(f32x4 a, f32x4 b) {
    bf16x8 r;
    r[0] = (short)f2bf(a[0]); r[1] = (short)f2bf(a[1]);
    r[2] = (short)f2bf(a[2]); r[3] = (short)f2bf(a[3]);
    r[4] = (short)f2bf(b[0]); r[5] = (short)f2bf(b[1]);
    r[6] = (short)f2bf(b[2]); r[7] = (short)f2bf(b[3]);
    return r;
}

// ---------------- Router: one wave per token ----------------
__global__ __launch_bounds__(256) void k_router(
    const float* __restrict__ x, const float* __restrict__ wr,
    float* __restrict__ out_logits, float* __restrict__ out_eidx,
    float* __restrict__ probs, int* __restrict__ eidx_i,
    int* __restrict__ counts, int* __restrict__ bucket)
{
    int tok  = (blockIdx.x * 256 + threadIdx.x) >> 6;
    int lane = threadIdx.x & 63;
    if (tok >= T_TOK) return;
    const float* xr = x + (size_t)tok * DIM;
    float acc[NE];
    #pragma unroll
    for (int e = 0; e < NE; e++) acc[e] = 0.f;
    #pragma unroll
    for (int j = 0; j < DIM / 64; j++) {
        int d = j * 64 + lane;
        float xv = xr[d];
        const float* wrow = wr + (size_t)d * NE;
        #pragma unroll
        for (int e = 0; e < NE; e++) acc[e] += xv * wrow[e];
    }
    #pragma unroll
    for (int e = 0; e < NE; e++) {
        #pragma unroll
        for (int off = 32; off >= 1; off >>= 1)
            acc[e] += __shfl_xor(acc[e], off);
    }
    if (lane == 0) {
        float mx = acc[0]; int mi = 0;
        #pragma unroll
        for (int e = 1; e < NE; e++) if (acc[e] > mx) { mx = acc[e]; mi = e; }
        float se = 0.f;
        #pragma unroll
        for (int e = 0; e < NE; e++) se += __expf(acc[e] - mx);
        #pragma unroll
        for (int e = 0; e < NE; e++) out_logits[(size_t)tok * NE + e] = acc[e];
        out_eidx[tok] = (float)mi;
        eidx_i[tok] = mi;
        probs[tok] = 1.f / se;
        int pos = atomicAdd(&counts[mi], 1);
        bucket[mi * T_TOK + pos] = tok;
    }
}

// ---------------- Compact ----------------
__global__ void k_compact(const int* __restrict__ counts, int* __restrict__ offsets,
                          const int* __restrict__ bucket, int* __restrict__ sorted)
{
    __shared__ int soff[NE + 1];
    if (threadIdx.x == 0) {
        int s = 0;
        for (int e = 0; e < NE; e++) { soff[e] = s; s += counts[e]; }
        soff[NE] = s;
        for (int e = 0; e <= NE; e++) offsets[e] = soff[e];
    }
    __syncthreads();
    for (int e = 0; e < NE; e++) {
        int c = counts[e], o = soff[e];
        for (int i = threadIdx.x; i < c; i += blockDim.x)
            sorted[o + i] = bucket[e * T_TOK + i];
    }
}

// ---------------- x -> bf16 (unsorted) ----------------
__global__ __launch_bounds__(256) void k_xconv(
    const float* __restrict__ x, unsigned short* __restrict__ Xb)
{
    int g0 = (blockIdx.x * 256 + threadIdx.x) * 8;
    if (g0 >= T_TOK * DIM) return;
    f32x4 a = *(const f32x4*)(x + g0);
    f32x4 b = *(const f32x4*)(x + g0 + 4);
    *(bf16x8*)(Xb + g0) = pack8(a, b);
}

// ---------------- transpose+convert: in[R][C] f32 -> out[C][R] bf16, per expert ----------------
// LDS layout swizzled: logical t[c][r] stored at t[c][(((r>>3)^(c>>4))&7)*8 + (r&7)]
__global__ __launch_bounds__(256) void k_tconv(
    const float* __restrict__ in, unsigned short* __restrict__ out, int R, int C)
{
    const size_t es = (size_t)R * C;
    in  += blockIdx.z * es;
    out += blockIdx.z * es;
    const int c0 = blockIdx.x * 64, r0 = blockIdx.y * 64;
    __shared__ unsigned short t[64][72];
    const int tr = threadIdx.x >> 2, tc = (threadIdx.x & 3) * 16;
    const float* src = in + (size_t)(r0 + tr) * C + c0 + tc;
    f32x4 v0 = *(const f32x4*)(src);
    f32x4 v1 = *(const f32x4*)(src + 4);
    f32x4 v2 = *(const f32x4*)(src + 8);
    f32x4 v3 = *(const f32x4*)(src + 12);
    const int xb = (tc >> 4) & 3;
    const int pr = (((tr >> 3) ^ xb) & 7) * 8 + (tr & 7);   // swizzled r-slot (same for all c in group)
    #pragma unroll
    for (int j = 0; j < 4; j++) {
        t[tc + j][pr]      = f2bf(v0[j]);
        t[tc + 4 + j][pr]  = f2bf(v1[j]);
        t[tc + 8 + j][pr]  = f2bf(v2[j]);
        t[tc + 12 + j][pr] = f2bf(v3[j]);
    }
    __syncthreads();
    const int oc = threadIdx.x >> 2, orr = (threadIdx.x & 3) * 16;
    const int rx = (oc >> 4) & 3;
    const int p0 = ((((orr >> 3) + 0) ^ rx) & 7) * 8;
    const int p1 = ((((orr >> 3) + 1) ^ rx) & 7) * 8;
    bf16x8 o0 = *(const bf16x8*)&t[oc][p0];   // logical r = orr..orr+7
    bf16x8 o1 = *(const bf16x8*)&t[oc][p1];   // logical r = orr+8..orr+15
    unsigned short* dst = out + (size_t)(c0 + oc) * R + r0 + orr;
    *(bf16x8*)(dst)     = o0;
    *(bf16x8*)(dst + 8) = o1;
}

// ---------------- init: out = b2[e]*prob ----------------
__global__ __launch_bounds__(256) void k_init(
    const float* __restrict__ b2, const int* __restrict__ eidx,
    const float* __restrict__ probs, float* __restrict__ outh)
{
    int tok = blockIdx.x;
    int e = eidx[tok];
    float p = probs[tok];
    const float* br = b2 + e * DIM;
    for (int d = threadIdx.x; d < DIM; d += 256)
        outh[(size_t)tok * DIM + d] = br[d] * p;
}

// ---------------- GEMM1: H = relu(X[sorted] @ w1t[e]^T + b1), 128x128, BK=32, dbuf pipeline ----------------
__global__ __launch_bounds__(256, 4) void k_gemm1(
    const unsigned short* __restrict__ Xb, const unsigned short* __restrict__ wt1,
    const float* __restrict__ b1, const int* __restrict__ sorted,
    const int* __restrict__ counts, const int* __restrict__ offsets,
    unsigned short* __restrict__ Hbuf)
{
    const int e  = blockIdx.y >> 5;
    const int ti = blockIdx.y & 31;
    const int cnt = counts[e];
    if (ti * 128 >= cnt) return;
    const int n0 = blockIdx.x * 128;
    const int off = offsets[e];
    const int rbase = ti * 128;
    const int tid = threadIdx.x, lane = tid & 63, wave = tid >> 6;
    const int wm = wave >> 1, wn = wave & 1;

    __shared__ unsigned short As[2][128][32];   // no pad: global_load_lds contiguity
    __shared__ unsigned short Bs[2][128][32];

    const int lr = lane >> 2;          // row within 16-row chunk
    const int ls = (lane & 3) * 8;     // bf16 col offset (16B segs)

    int r0 = rbase + wave * 32 + lr;        if (r0 >= cnt) r0 = rbase;
    int r1 = rbase + wave * 32 + 16 + lr;   if (r1 >= cnt) r1 = rbase;
    const unsigned short* aP0 = Xb + (size_t)sorted[off + r0] * DIM + ls;   // fused gather
    const unsigned short* aP1 = Xb + (size_t)sorted[off + r1] * DIM + ls;
    const unsigned short* wB  = wt1 + (size_t)e * FF * DIM;                 // [FF][DIM]
    const unsigned short* bP0 = wB + (size_t)(n0 + wave * 32 + lr) * DIM + ls;
    const unsigned short* bP1 = wB + (size_t)(n0 + wave * 32 + 16 + lr) * DIM + ls;

    f32x4 acc[4][4];
    #pragma unroll
    for (int i = 0; i < 4; i++)
        #pragma unroll
        for (int j = 0; j < 4; j++) acc[i][j] = (f32x4)0.f;

    const int lrow = lane & 15, kq = lane >> 4;
    const int NIT = DIM / 32;

    // prologue: tile 0 -> buf 0
    g2l16(aP0, &As[0][wave * 32][0]);
    g2l16(aP1, &As[0][wave * 32 + 16][0]);
    g2l16(bP0, &Bs[0][wave * 32][0]);
    g2l16(bP1, &Bs[0][wave * 32 + 16][0]);

    for (int it = 0; it < NIT; ++it) {
        const int buf = it & 1;
        if (it == 0) {
            __syncthreads();                  // drains vmcnt+lgkm, full fence
        } else {
            WAIT_VM0();                       // own tile-it loads done
            RAW_BARRIER();                    // tile it visible; prefetch k+1 stays in flight next
        }
        if (it + 1 < NIT) {
            const int nb_ = (it + 1) & 1;
            const int ko = (it + 1) * 32;
            g2l16(aP0 + ko, &As[nb_][wave * 32][0]);
            g2l16(aP1 + ko, &As[nb_][wave * 32 + 16][0]);
            g2l16(bP0 + ko, &Bs[nb_][wave * 32][0]);
            g2l16(bP1 + ko, &Bs[nb_][wave * 32 + 16][0]);
        }
        bf16x8 af[4], bfv[4];
        #pragma unroll
        for (int i = 0; i < 4; i++)
            af[i] = *(const bf16x8*)&As[buf][wm * 64 + i * 16 + lrow][kq * 8];
        #pragma unroll
        for (int i = 0; i < 4; i++)
            bfv[i] = *(const bf16x8*)&Bs[buf][wn * 64 + i * 16 + lrow][kq * 8];
        #pragma unroll
        for (int mi = 0; mi < 4; mi++)
            #pragma unroll
            for (int ni = 0; ni < 4; ni++)
                acc[mi][ni] = __builtin_amdgcn_mfma_f32_16x16x32_bf16(
                    af[mi], bfv[ni], acc[mi][ni], 0, 0, 0);
    }

    const int quad = lane >> 4;
    #pragma unroll
    for (int ni = 0; ni < 4; ni++) {
        int gn = n0 + wn * 64 + ni * 16 + lrow;
        float bias = b1[e * FF + gn];
        #pragma unroll
        for (int mi = 0; mi < 4; mi++) {
            f32x4 v = acc[mi][ni];
            #pragma unroll
            for (int r = 0; r < 4; r++) {
                int ml = rbase + wm * 64 + mi * 16 + quad * 4 + r;
                if (ml < cnt) {
                    float h = v[r] + bias; h = h > 0.f ? h : 0.f;
                    Hbuf[(size_t)(off + ml) * FF + gn] = f2bf(h);
                }
            }
        }
    }
}

// ---------------- GEMM2: out += (H @ w2t[e]^T)*prob, 128x128, split-K x4, dbuf pipeline ----------------
__global__ __launch_bounds__(256, 4) void k_gemm2(
    const unsigned short* __restrict__ Hbuf, const unsigned short* __restrict__ wt2,
    const int* __restrict__ sorted, const int* __restrict__ counts,
    const int* __restrict__ offsets, const float* __restrict__ probs,
    float* __restrict__ outh)
{
    const int e  = blockIdx.y >> 5;
    const int ti = blockIdx.y & 31;
    const int cnt = counts[e];
    if (ti * 128 >= cnt) return;
    const int n0 = blockIdx.x * 128;          // N=768 -> 6 tiles
    const int kc = blockIdx.z;                // K chunk of 768
    const int off = offsets[e];
    const int rbase = ti * 128;
    const int tid = threadIdx.x, lane = tid & 63, wave = tid >> 6;
    const int wm = wave >> 1, wn = wave & 1;

    __shared__ unsigned short As[2][128][32];
    __shared__ unsigned short Bs[2][128][32];
    __shared__ int   s_tok[128];
    __shared__ float s_prob[128];

    if (tid < 128) {
        int rr = rbase + tid; if (rr >= cnt) rr = rbase;
        int tk = sorted[off + rr];
        s_tok[tid]  = tk;
        s_prob[tid] = probs[tk];
    }

    const int lr = lane >> 2, ls = (lane & 3) * 8;
    int r0 = rbase + wave * 32 + lr;        if (r0 >= cnt) r0 = rbase;
    int r1 = rbase + wave * 32 + 16 + lr;   if (r1 >= cnt) r1 = rbase;
    const unsigned short* aP0 = Hbuf + (size_t)(off + r0) * FF + kc * 768 + ls;
    const unsigned short* aP1 = Hbuf + (size_t)(off + r1) * FF + kc * 768 + ls;
    const unsigned short* wB  = wt2 + (size_t)e * DIM * FF;                 // [DIM][FF]
    const unsigned short* bP0 = wB + (size_t)(n0 + wave * 32 + lr) * FF + kc * 768 + ls;
    const unsigned short* bP1 = wB + (size_t)(n0 + wave * 32 + 16 + lr) * FF + kc * 768 + ls;

    f32x4 acc[4][4];
    #pragma unroll
    for (int i = 0; i < 4; i++)
        #pragma unroll
        for (int j = 0; j < 4; j++) acc[i][j] = (f32x4)0.f;

    const int lrow = lane & 15, kq = lane >> 4;
    const int NIT = 768 / 32;

    g2l16(aP0, &As[0][wave * 32][0]);
    g2l16(aP1, &As[0][wave * 32 + 16][0]);
    g2l16(bP0, &Bs[0][wave * 32][0]);
    g2l16(bP1, &Bs[0][wave * 32 + 16][0]);

    for (int it = 0; it < NIT; ++it) {
        const int buf = it & 1;
        if (it == 0) {
            __syncthreads();                  // also fences s_tok/s_prob ds_writes
        } else {
            WAIT_VM0();
            RAW_BARRIER();
        }
        if (it + 1 < NIT) {
            const int nb_ = (it + 1) & 1;
            const int ko = (it + 1) * 32;
            g2l16(aP0 + ko, &As[nb_][wave * 32][0]);
            g2l16(aP1 + ko, &As[nb_][wave * 32 + 16][0]);
            g2l16(bP0 + ko, &Bs[nb_][wave * 32][0]);
            g2l16(bP1 + ko, &Bs[nb_][wave * 32 + 16][0]);
        }
        bf16x8 af[4], bfv[4];
        #pragma unroll
        for (int i = 0; i < 4; i++)
            af[i] = *(const bf16x8*)&As[buf][wm * 64 + i * 16 + lrow][kq * 8];
        #pragma unroll
        for (int i = 0; i < 4; i++)
            bfv[i] = *(const bf16x8*)&Bs[buf][wn * 64 + i * 16 + lrow][kq * 8];
        #pragma unroll
        for (int mi = 0; mi < 4; mi++)
            #pragma unroll
            for (int ni = 0; ni < 4; ni++)
                acc[mi][ni] = __builtin_amdgcn_mfma_f32_16x16x32_bf16(
                    af[mi], bfv[ni], acc[mi][ni], 0, 0, 0);
    }

    const int quad = lane >> 4;
    #pragma unroll
    for (int ni = 0; ni < 4; ni++) {
        int gn = n0 + wn * 64 + ni * 16 + lrow;
        #pragma unroll
        for (int mi = 0; mi < 4; mi++) {
            f32x4 v = acc[mi][ni];
            #pragma unroll
            for (int r = 0; r < 4; r++) {
                int mloc = wm * 64 + mi * 16 + quad * 4 + r;
                if (rbase + mloc < cnt) {
                    atomicAdd(&outh[(size_t)s_tok[mloc] * DIM + gn], v[r] * s_prob[mloc]);
                }
            }
        }
    }
}

// ================= Fallback path (R2 kernels, used only if ws too small) =================
__global__ __launch_bounds__(256) void k_gather_fb(
    const float* __restrict__ x, const int* __restrict__ sorted,
    unsigned short* __restrict__ Xg)
{
    int g0 = (blockIdx.x * 256 + threadIdx.x) * 8;
    if (g0 >= T_TOK * DIM) return;
    int row = g0 / DIM, col = g0 - row * DIM;
    const float* src = x + (size_t)sorted[row] * DIM + col;
    f32x4 a = *(const f32x4*)(src);
    f32x4 b = *(const f32x4*)(src + 4);
    *(bf16x8*)(Xg + (size_t)row * DIM + col) = pack8(a, b);
}

__global__ __launch_bounds__(256, 3) void k_gemm1_fb(
    const unsigned short* __restrict__ Xg, const float* __restrict__ w1,
    const float* __restrict__ b1, const int* __restrict__ counts,
    const int* __restrict__ offsets, unsigned short* __restrict__ Hbuf)
{
    const int e   = blockIdx.y >> 5;
    const int ti  = blockIdx.y & 31;
    const int cnt = counts[e];
    if (ti * 128 >= cnt) return;
    const int n0    = blockIdx.x * 128;
    const int off   = offsets[e];
    const int rbase = ti * 128;
    const int rmax  = cnt - rbase - 1;
    const int tid   = threadIdx.x;
    const int lane  = tid & 63;
    const int wave  = tid >> 6;
    const int wm = wave >> 1, wn = wave & 1;
    __shared__ unsigned short As[128][72];
    __shared__ unsigned short Bs[128][72];
    const float* w1e = w1 + (size_t)e * DIM * FF;
    f32x4 acc[4][4];
    #pragma unroll
    for (int i = 0; i < 4; i++)
        #pragma unroll
        for (int j = 0; j < 4; j++) acc[i][j] = (f32x4)0.f;
    const int arow = tid >> 1, aseg = tid & 1;
    const int are  = (arow <= rmax) ? arow : 0;
    const unsigned short* abase = Xg + (size_t)(off + rbase + are) * DIM + aseg * 32;
    const int kb = tid >> 5, nb = tid & 31;
    const float* bbase = w1e + (size_t)kb * 8 * FF + n0 + nb * 4;
    bf16x8 aR[4];
    f32x4  bR[8];
    #pragma unroll
    for (int j = 0; j < 4; j++) aR[j] = *(const bf16x8*)(abase + j * 8);
    #pragma unroll
    for (int r = 0; r < 8; r++) bR[r] = *(const f32x4*)(bbase + (size_t)r * FF);
    const int lrow = lane & 15, kq = lane >> 4;
    for (int it = 0; it < DIM / 64; ++it) {
        __syncthreads();
        #pragma unroll
        for (int j = 0; j < 4; j++)
            *(bf16x8*)&As[arow][aseg * 32 + j * 8] = aR[j];
        #pragma unroll
        for (int j = 0; j < 4; j++) {
            bf16x8 c;
            #pragma unroll
            for (int r = 0; r < 8; r++) c[r] = (short)f2bf(bR[r][j]);
            *(bf16x8*)&Bs[nb * 4 + j][kb * 8] = c;
        }
        __syncthreads();
        if (it + 1 < DIM / 64) {
            const unsigned short* an = abase + (it + 1) * 64;
            #pragma unroll
            for (int j = 0; j < 4; j++) aR[j] = *(const bf16x8*)(an + j * 8);
            const float* bn = bbase + (size_t)(it + 1) * 64 * FF;
            #pragma unroll
            for (int r = 0; r < 8; r++) bR[r] = *(const f32x4*)(bn + (size_t)r * FF);
        }
        #pragma unroll
        for (int ks = 0; ks < 2; ks++) {
            bf16x8 af[4], bfr[4];
            #pragma unroll
            for (int i = 0; i < 4; i++)
                af[i] = *(const bf16x8*)&As[wm * 64 + i * 16 + lrow][ks * 32 + kq * 8];
            #pragma unroll
            for (int i = 0; i < 4; i++)
                bfr[i] = *(const bf16x8*)&Bs[wn * 64 + i * 16 + lrow][ks * 32 + kq * 8];
            #pragma unroll
            for (int mi = 0; mi < 4; mi++)
                #pragma unroll
                for (int ni = 0; ni < 4; ni++)
                    acc[mi][ni] = __builtin_amdgcn_mfma_f32_16x16x32_bf16(
                        af[mi], bfr[ni], acc[mi][ni], 0, 0, 0);
        }
    }
    const int quad = lane >> 4;
    #pragma unroll
    for (int ni = 0; ni < 4; ni++) {
        int gn = n0 + wn * 64 + ni * 16 + lrow;
        float bias = b1[e * FF + gn];
        #pragma unroll
        for (int mi = 0; mi < 4; mi++) {
            f32x4 v = acc[mi][ni];
            #pragma unroll
            for (int r = 0; r < 4; r++) {
                int ml = wm * 64 + mi * 16 + quad * 4 + r;
                if (rbase + ml < cnt) {
                    float h = v[r] + bias;
                    h = h > 0.f ? h : 0.f;
                    Hbuf[(size_t)(off + rbase + ml) * FF + gn] = f2bf(h);
                }
            }
        }
    }
}

__global__ __launch_bounds__(256, 4) void k_gemm2_fb(
    const unsigned short* __restrict__ Hbuf, const float* __restrict__ w2,
    const float* __restrict__ b2, const int* __restrict__ sorted,
    const int* __restrict__ counts, const int* __restrict__ offsets,
    const float* __restrict__ probs, float* __restrict__ outh)
{
    const int e   = blockIdx.y >> 5;
    const int ti  = blockIdx.y & 31;
    const int cnt = counts[e];
    if (ti * 128 >= cnt) return;
    const int n0    = blockIdx.x * 64;
    const int off   = offsets[e];
    const int rbase = ti * 128;
    const int rmax  = cnt - rbase - 1;
    const int tid   = threadIdx.x;
    const int lane  = tid & 63;
    const int wave  = tid >> 6;
    const int wm = wave >> 1, wn = wave & 1;
    __shared__ unsigned short As[128][72];
    __shared__ unsigned short Bs[64][72];
    __shared__ int   s_tok[128];
    __shared__ float s_prob[128];
    if (tid < 128) {
        int r = rbase + tid;
        int tk = sorted[off + ((r < cnt) ? r : rbase)];
        s_tok[tid]  = tk;
        s_prob[tid] = probs[tk];
    }
    const float* w2e = w2 + (size_t)e * FF * DIM;
    f32x4 acc[4][2];
    #pragma unroll
    for (int i = 0; i < 4; i++)
        #pragma unroll
        for (int j = 0; j < 2; j++) acc[i][j] = (f32x4)0.f;
    const int arow = tid >> 1, aseg = tid & 1;
    const int are  = (arow <= rmax) ? arow : 0;
    const unsigned short* abase = Hbuf + (size_t)(off + rbase + are) * FF + aseg * 32;
    const int kb = tid >> 5, nb = tid & 31;
    const float* bbase = w2e + (size_t)kb * 8 * DIM + n0 + nb * 2;
    bf16x8 aR[4];
    f32x2  bR[8];
    #pragma unroll
    for (int j = 0; j < 4; j++) aR[j] = *(const bf16x8*)(abase + j * 8);
    #pragma unroll
    for (int r = 0; r < 8; r++) bR[r] = *(const f32x2*)(bbase + (size_t)r * DIM);
    const int lrow = lane & 15, kq = lane >> 4;
    for (int it = 0; it < FF / 64; ++it) {
        __syncthreads();
        #pragma unroll
        for (int j = 0; j < 4; j++)
            *(bf16x8*)&As[arow][aseg * 32 + j * 8] = aR[j];
        {
            bf16x8 c0, c1;
            #pragma unroll
            for (int r = 0; r < 8; r++) { c0[r] = (short)f2bf(bR[r][0]); c1[r] = (short)f2bf(bR[r][1]); }
            *(bf16x8*)&Bs[nb * 2 + 0][kb * 8] = c0;
            *(bf16x8*)&Bs[nb * 2 + 1][kb * 8] = c1;
        }
        __syncthreads();
        if (it + 1 < FF / 64) {
            const unsigned short* an = abase + (it + 1) * 64;
            #pragma unroll
            for (int j = 0; j < 4; j++) aR[j] = *(const bf16x8*)(an + j * 8);
            const float* bn = bbase + (size_t)(it + 1) * 64 * DIM;
            #pragma unroll
            for (int r = 0; r < 8; r++) bR[r] = *(const f32x2*)(bn + (size_t)r * DIM);
        }
        #pragma unroll
        for (int ks = 0; ks < 2; ks++) {
            bf16x8 af[4], bfr[2];
            #pragma unroll
            for (int i = 0; i < 4; i++)
                af[i] = *(const bf16x8*)&As[wm * 64 + i * 16 + lrow][ks * 32 + kq * 8];
            #pragma unroll
            for (int i = 0; i < 2; i++)
                bfr[i] = *(const bf16x8*)&Bs[wn * 32 + i * 16 + lrow][ks * 32 + kq * 8];
            #pragma unroll
            for (int mi = 0; mi < 4; mi++)
                #pragma unroll
                for (int ni = 0; ni < 2; ni++)
                    acc[mi][ni] = __builtin_amdgcn_mfma_f32_16x16x32_bf16(
                        af[mi], bfr[ni], acc[mi][ni], 0, 0, 0);
        }
    }
    const int quad = lane >> 4;
    #pragma unroll
    for (int ni = 0; ni < 2; ni++) {
        int gn = n0 + wn * 32 + ni * 16 + lrow;
        float bias = b2[e * DIM + gn];
        #pragma unroll
        for (int mi = 0; mi < 4; mi++) {
            f32x4 v = acc[mi][ni];
            #pragma unroll
            for (int r = 0; r < 4; r++) {
                int ml = wm * 64 + mi * 16 + quad * 4 + r;
                if (rbase + ml < cnt) {
                    outh[(size_t)s_tok[ml] * DIM + gn] = (v[r] + bias) * s_prob[ml];
                }
            }
        }
    }
}

extern "C" void kernel_launch(void* const* d_in, const int* in_sizes, int n_in,
                              void* d_out, int out_size, void* d_ws, size_t ws_size,
                              hipStream_t stream) {
    (void)in_sizes; (void)n_in; (void)out_size;
    const float* x  = (const float*)d_in[0];
    const float* wr = (const float*)d_in[1];
    const float* w1 = (const float*)d_in[2];
    const float* b1 = (const float*)d_in[3];
    const float* w2 = (const float*)d_in[4];
    const float* b2 = (const float*)d_in[5];

    float* out_hidden = (float*)d_out;                        // [T, D]
    float* out_logits = out_hidden + (size_t)T_TOK * DIM;     // [T, E]
    float* out_eidx   = out_logits + (size_t)T_TOK * NE;      // [T]

    char* ws = (char*)d_ws;
    int*   counts  = (int*)(ws + 0);
    int*   offsets = (int*)(ws + 64);
    float* probs   = (float*)(ws + 128);
    int*   eidx_i  = (int*)(ws + 16512);
    int*   sorted  = (int*)(ws + 32896);
    int*   bucket  = (int*)(ws + 49280);
    unsigned short* Xb   = (unsigned short*)(ws + 180352);    // T*DIM bf16
    unsigned short* Hbuf = (unsigned short*)(ws + 6471808);   // T*FF bf16
    unsigned short* wt1  = (unsigned short*)(ws + 31637632);  // E*FF*DIM bf16 [e][f][d]
    unsigned short* wt2  = (unsigned short*)(ws + 69386368);  // E*DIM*FF bf16 [e][d][f]
    const size_t NEED = 107135104;

    hipMemsetAsync(counts, 0, 32, stream);
    k_router<<<dim3(T_TOK / 4), dim3(256), 0, stream>>>(
        x, wr, out_logits, out_eidx, probs, eidx_i, counts, bucket);
    k_compact<<<dim3(1), dim3(256), 0, stream>>>(counts, offsets, bucket, sorted);

    if (ws_size >= NEED) {
        k_xconv<<<dim3(T_TOK * DIM / 8 / 256), dim3(256), 0, stream>>>(x, Xb);
        k_tconv<<<dim3(FF / 64, DIM / 64, NE), dim3(256), 0, stream>>>(w1, wt1, DIM, FF);
        k_tconv<<<dim3(DIM / 64, FF / 64, NE), dim3(256), 0, stream>>>(w2, wt2, FF, DIM);
        k_init<<<dim3(T_TOK), dim3(256), 0, stream>>>(b2, eidx_i, probs, out_hidden);
        k_gemm1<<<dim3(FF / 128, NE * 32), dim3(256), 0, stream>>>(
            Xb, wt1, b1, sorted, counts, offsets, Hbuf);
        k_gemm2<<<dim3(DIM / 128, NE * 32, 4), dim3(256), 0, stream>>>(
            Hbuf, wt2, sorted, counts, offsets, probs, out_hidden);
    } else {
        k_gather_fb<<<dim3(T_TOK * DIM / 8 / 256), dim3(256), 0, stream>>>(x, sorted, Xb);
        k_gemm1_fb<<<dim3(FF / 128, NE * 32), dim3(256), 0, stream>>>(
            Xb, w1, b1, counts, offsets, Hbuf);
        k_gemm2_fb<<<dim3(DIM / 64, NE * 32), dim3(256), 0, stream>>>(
            Hbuf, w2, b2, sorted, counts, offsets, probs, out_hidden);
    }
}

// Round 5
// 379.573 us; speedup vs baseline: 1.0392x; 1.0392x over previous
//
#include <hip/hip_runtime.h>
#include <hip/hip_bf16.h>

#define T_TOK 4096
#define DIM   768
#define FF    3072
#define NE    8

typedef __attribute__((ext_vector_type(8))) short bf16x8;
typedef __attribute__((ext_vector_type(4))) short bf16x4;
typedef __attribute__((ext_vector_type(4))) float f32x4;
typedef __attribute__((ext_vector_type(2))) float f32x2;

typedef __attribute__((address_space(1))) void gvoid_t;
typedef __attribute__((address_space(3))) void lvoid_t;

__device__ __forceinline__ void g2l16(const void* g, void* l) {
    // async global->LDS, 16B per lane; LDS dest must be wave-uniform base
    __builtin_amdgcn_global_load_lds((gvoid_t*)(void*)g, (lvoid_t*)l, 16, 0, 0);
}

// gfx9 waitcnt simm16: vm[3:0] | exp[6:4] | lgkm[11:8] | vm_hi[15:14]
#define WAIT_VM0() __builtin_amdgcn_s_waitcnt(0x0F70)
#define WAIT_VM4() __builtin_amdgcn_s_waitcnt(0x0F74)
#define RAW_BARRIER() asm volatile("s_barrier" ::: "memory")

__device__ __forceinline__ unsigned short f2bf(float f) {
    union { float f; unsigned int u; } v; v.f = f;
    unsigned int u = v.u;
    u += 0x7FFFu + ((u >> 16) & 1u);   // round-to-nearest-even
    return (unsigned short)(u >> 16);
}

__device__ __forceinline__ bf16x8 pack8(f32x4 a, f32x4 b) {
    bf16x8 r;
    r[0] = (short)f2bf(a[0]); r[1] = (short)f2bf(a[1]);
    r[2] = (short)f2bf(a[2]); r[3] = (short)f2bf(a[3]);
    r[4] = (short)f2bf(b[0]); r[5] = (short)f2bf(b[1]);
    r[6] = (short)f2bf(b[2]); r[7] = (short)f2bf(b[3]);
    return r;
}

// ---------------- Router: one wave per token ----------------
__global__ __launch_bounds__(256) void k_router(
    const float* __restrict__ x, const float* __restrict__ wr,
    float* __restrict__ out_logits, float* __restrict__ out_eidx,
    float* __restrict__ probs, int* __restrict__ eidx_i,
    int* __restrict__ counts, int* __restrict__ bucket)
{
    int tok  = (blockIdx.x * 256 + threadIdx.x) >> 6;
    int lane = threadIdx.x & 63;
    if (tok >= T_TOK) return;
    const float* xr = x + (size_t)tok * DIM;
    float acc[NE];
    #pragma unroll
    for (int e = 0; e < NE; e++) acc[e] = 0.f;
    #pragma unroll
    for (int j = 0; j < DIM / 64; j++) {
        int d = j * 64 + lane;
        float xv = xr[d];
        const float* wrow = wr + (size_t)d * NE;
        #pragma unroll
        for (int e = 0; e < NE; e++) acc[e] += xv * wrow[e];
    }
    #pragma unroll
    for (int e = 0; e < NE; e++) {
        #pragma unroll
        for (int off = 32; off >= 1; off >>= 1)
            acc[e] += __shfl_xor(acc[e], off);
    }
    if (lane == 0) {
        float mx = acc[0]; int mi = 0;
        #pragma unroll
        for (int e = 1; e < NE; e++) if (acc[e] > mx) { mx = acc[e]; mi = e; }
        float se = 0.f;
        #pragma unroll
        for (int e = 0; e < NE; e++) se += __expf(acc[e] - mx);
        #pragma unroll
        for (int e = 0; e < NE; e++) out_logits[(size_t)tok * NE + e] = acc[e];
        out_eidx[tok] = (float)mi;
        eidx_i[tok] = mi;
        probs[tok] = 1.f / se;
        int pos = atomicAdd(&counts[mi], 1);
        bucket[mi * T_TOK + pos] = tok;
    }
}

// ---------------- Compact ----------------
__global__ void k_compact(const int* __restrict__ counts, int* __restrict__ offsets,
                          const int* __restrict__ bucket, int* __restrict__ sorted)
{
    __shared__ int soff[NE + 1];
    if (threadIdx.x == 0) {
        int s = 0;
        for (int e = 0; e < NE; e++) { soff[e] = s; s += counts[e]; }
        soff[NE] = s;
        for (int e = 0; e <= NE; e++) offsets[e] = soff[e];
    }
    __syncthreads();
    for (int e = 0; e < NE; e++) {
        int c = counts[e], o = soff[e];
        for (int i = threadIdx.x; i < c; i += blockDim.x)
            sorted[o + i] = bucket[e * T_TOK + i];
    }
}

// ---------------- x -> bf16 (unsorted) ----------------
__global__ __launch_bounds__(256) void k_xconv(
    const float* __restrict__ x, unsigned short* __restrict__ Xb)
{
    int g0 = (blockIdx.x * 256 + threadIdx.x) * 8;
    if (g0 >= T_TOK * DIM) return;
    f32x4 a = *(const f32x4*)(x + g0);
    f32x4 b = *(const f32x4*)(x + g0 + 4);
    *(bf16x8*)(Xb + g0) = pack8(a, b);
}

// ---------------- transpose+convert: in[R][C] f32 -> out[C][R] bf16, per expert ----------------
__global__ __launch_bounds__(256) void k_tconv(
    const float* __restrict__ in, unsigned short* __restrict__ out, int R, int C)
{
    const size_t es = (size_t)R * C;
    in  += blockIdx.z * es;
    out += blockIdx.z * es;
    const int c0 = blockIdx.x * 64, r0 = blockIdx.y * 64;
    __shared__ unsigned short t[64][72];
    const int tr = threadIdx.x >> 2, tc = (threadIdx.x & 3) * 16;
    const float* src = in + (size_t)(r0 + tr) * C + c0 + tc;
    f32x4 v0 = *(const f32x4*)(src);
    f32x4 v1 = *(const f32x4*)(src + 4);
    f32x4 v2 = *(const f32x4*)(src + 8);
    f32x4 v3 = *(const f32x4*)(src + 12);
    const int xb = (tc >> 4) & 3;
    const int pr = (((tr >> 3) ^ xb) & 7) * 8 + (tr & 7);   // swizzled r-slot
    #pragma unroll
    for (int j = 0; j < 4; j++) {
        t[tc + j][pr]      = f2bf(v0[j]);
        t[tc + 4 + j][pr]  = f2bf(v1[j]);
        t[tc + 8 + j][pr]  = f2bf(v2[j]);
        t[tc + 12 + j][pr] = f2bf(v3[j]);
    }
    __syncthreads();
    const int oc = threadIdx.x >> 2, orr = (threadIdx.x & 3) * 16;
    const int rx = (oc >> 4) & 3;
    const int p0 = ((((orr >> 3) + 0) ^ rx) & 7) * 8;
    const int p1 = ((((orr >> 3) + 1) ^ rx) & 7) * 8;
    bf16x8 o0 = *(const bf16x8*)&t[oc][p0];
    bf16x8 o1 = *(const bf16x8*)&t[oc][p1];
    unsigned short* dst = out + (size_t)(c0 + oc) * R + r0 + orr;
    *(bf16x8*)(dst)     = o0;
    *(bf16x8*)(dst + 8) = o1;
}

// ---------------- fin: out = prob * (P0+P1+P2 + b2[e]) ----------------
__global__ __launch_bounds__(256) void k_fin(
    const float* __restrict__ P, const float* __restrict__ b2,
    const int* __restrict__ eidx, const float* __restrict__ probs,
    float* __restrict__ outh)
{
    const int tok = blockIdx.x;
    const float p = probs[tok];
    const int e = eidx[tok];
    const float* p0 = P + (size_t)tok * DIM;
    const float* p1 = p0 + (size_t)T_TOK * DIM;
    const float* p2 = p1 + (size_t)T_TOK * DIM;
    const float* br = b2 + e * DIM;
    float* o = outh + (size_t)tok * DIM;
    for (int d = threadIdx.x; d < DIM; d += 256)
        o[d] = p * (p0[d] + p1[d] + p2[d] + br[d]);
}

// ---------------- GEMM1: H = relu(X[sorted] @ w1t[e]^T + b1), 128x128, BK=32, 3-buf depth-2 ----------------
__global__ __launch_bounds__(256, 3) void k_gemm1(
    const unsigned short* __restrict__ Xb, const unsigned short* __restrict__ wt1,
    const float* __restrict__ b1, const int* __restrict__ sorted,
    const int* __restrict__ counts, const int* __restrict__ offsets,
    unsigned short* __restrict__ Hbuf)
{
    const int e  = blockIdx.y >> 5;
    const int ti = blockIdx.y & 31;
    const int cnt = counts[e];
    if (ti * 128 >= cnt) return;
    const int n0 = blockIdx.x * 128;
    const int off = offsets[e];
    const int rbase = ti * 128;
    const int tid = threadIdx.x, lane = tid & 63, wave = tid >> 6;
    const int wm = wave >> 1, wn = wave & 1;

    __shared__ unsigned short As[3][128][32];
    __shared__ unsigned short Bs[3][128][32];

    const int lr = lane >> 2;
    const int ls = (lane & 3) * 8;

    int r0 = rbase + wave * 32 + lr;        if (r0 >= cnt) r0 = rbase;
    int r1 = rbase + wave * 32 + 16 + lr;   if (r1 >= cnt) r1 = rbase;
    const unsigned short* aP0 = Xb + (size_t)sorted[off + r0] * DIM + ls;   // fused gather
    const unsigned short* aP1 = Xb + (size_t)sorted[off + r1] * DIM + ls;
    const unsigned short* wB  = wt1 + (size_t)e * FF * DIM;                 // [FF][DIM]
    const unsigned short* bP0 = wB + (size_t)(n0 + wave * 32 + lr) * DIM + ls;
    const unsigned short* bP1 = wB + (size_t)(n0 + wave * 32 + 16 + lr) * DIM + ls;

    f32x4 acc[4][4];
    #pragma unroll
    for (int i = 0; i < 4; i++)
        #pragma unroll
        for (int j = 0; j < 4; j++) acc[i][j] = (f32x4)0.f;

    const int lrow = lane & 15, kq = lane >> 4;
    const int NIT = DIM / 32;   // 24

    // prologue: tile0; drain; tile1
    g2l16(aP0, &As[0][wave * 32][0]);
    g2l16(aP1, &As[0][wave * 32 + 16][0]);
    g2l16(bP0, &Bs[0][wave * 32][0]);
    g2l16(bP1, &Bs[0][wave * 32 + 16][0]);
    __syncthreads();
    g2l16(aP0 + 32, &As[1][wave * 32][0]);
    g2l16(aP1 + 32, &As[1][wave * 32 + 16][0]);
    g2l16(bP0 + 32, &Bs[1][wave * 32][0]);
    g2l16(bP1 + 32, &Bs[1][wave * 32 + 16][0]);

    for (int it = 0; it < NIT; ++it) {
        const int buf = it % 3;
        if (it > 0) {
            WAIT_VM4();       // oldest tile (it) done; tile it+1 stays in flight
            RAW_BARRIER();
        }
        if (it + 2 < NIT) {
            const int nb_ = (it + 2) % 3;
            const int ko = (it + 2) * 32;
            g2l16(aP0 + ko, &As[nb_][wave * 32][0]);
            g2l16(aP1 + ko, &As[nb_][wave * 32 + 16][0]);
            g2l16(bP0 + ko, &Bs[nb_][wave * 32][0]);
            g2l16(bP1 + ko, &Bs[nb_][wave * 32 + 16][0]);
        }
        bf16x8 af[4], bfv[4];
        #pragma unroll
        for (int i = 0; i < 4; i++)
            af[i] = *(const bf16x8*)&As[buf][wm * 64 + i * 16 + lrow][kq * 8];
        #pragma unroll
        for (int i = 0; i < 4; i++)
            bfv[i] = *(const bf16x8*)&Bs[buf][wn * 64 + i * 16 + lrow][kq * 8];
        #pragma unroll
        for (int mi = 0; mi < 4; mi++)
            #pragma unroll
            for (int ni = 0; ni < 4; ni++)
                acc[mi][ni] = __builtin_amdgcn_mfma_f32_16x16x32_bf16(
                    af[mi], bfv[ni], acc[mi][ni], 0, 0, 0);
    }

    const int quad = lane >> 4;
    #pragma unroll
    for (int ni = 0; ni < 4; ni++) {
        int gn = n0 + wn * 64 + ni * 16 + lrow;
        float bias = b1[e * FF + gn];
        #pragma unroll
        for (int mi = 0; mi < 4; mi++) {
            f32x4 v = acc[mi][ni];
            #pragma unroll
            for (int r = 0; r < 4; r++) {
                int ml = rbase + wm * 64 + mi * 16 + quad * 4 + r;
                if (ml < cnt) {
                    float h = v[r] + bias; h = h > 0.f ? h : 0.f;
                    Hbuf[(size_t)(off + ml) * FF + gn] = f2bf(h);
                }
            }
        }
    }
}

// ---------------- GEMM2: P[kc] = H @ w2t[e]^T chunk, 128x128, split-K x3, plain stores ----------------
__global__ __launch_bounds__(256, 3) void k_gemm2(
    const unsigned short* __restrict__ Hbuf, const unsigned short* __restrict__ wt2,
    const int* __restrict__ sorted, const int* __restrict__ counts,
    const int* __restrict__ offsets, float* __restrict__ Pbuf)
{
    const int e  = blockIdx.y >> 5;
    const int ti = blockIdx.y & 31;
    const int cnt = counts[e];
    if (ti * 128 >= cnt) return;
    const int n0 = blockIdx.x * 128;          // N=768 -> 6 tiles
    const int kc = blockIdx.z;                // 3 chunks of K=1024
    const int off = offsets[e];
    const int rbase = ti * 128;
    const int tid = threadIdx.x, lane = tid & 63, wave = tid >> 6;
    const int wm = wave >> 1, wn = wave & 1;

    __shared__ unsigned short As[3][128][32];
    __shared__ unsigned short Bs[3][128][32];
    __shared__ int s_tok[128];

    if (tid < 128) {
        int rr = rbase + tid; if (rr >= cnt) rr = rbase;
        s_tok[tid] = sorted[off + rr];
    }

    const int lr = lane >> 2, ls = (lane & 3) * 8;
    int r0 = rbase + wave * 32 + lr;        if (r0 >= cnt) r0 = rbase;
    int r1 = rbase + wave * 32 + 16 + lr;   if (r1 >= cnt) r1 = rbase;
    const unsigned short* aP0 = Hbuf + (size_t)(off + r0) * FF + kc * 1024 + ls;
    const unsigned short* aP1 = Hbuf + (size_t)(off + r1) * FF + kc * 1024 + ls;
    const unsigned short* wB  = wt2 + (size_t)e * DIM * FF;                 // [DIM][FF]
    const unsigned short* bP0 = wB + (size_t)(n0 + wave * 32 + lr) * FF + kc * 1024 + ls;
    const unsigned short* bP1 = wB + (size_t)(n0 + wave * 32 + 16 + lr) * FF + kc * 1024 + ls;

    f32x4 acc[4][4];
    #pragma unroll
    for (int i = 0; i < 4; i++)
        #pragma unroll
        for (int j = 0; j < 4; j++) acc[i][j] = (f32x4)0.f;

    const int lrow = lane & 15, kq = lane >> 4;
    const int NIT = 1024 / 32;   // 32

    g2l16(aP0, &As[0][wave * 32][0]);
    g2l16(aP1, &As[0][wave * 32 + 16][0]);
    g2l16(bP0, &Bs[0][wave * 32][0]);
    g2l16(bP1, &Bs[0][wave * 32 + 16][0]);
    __syncthreads();                          // also fences s_tok
    g2l16(aP0 + 32, &As[1][wave * 32][0]);
    g2l16(aP1 + 32, &As[1][wave * 32 + 16][0]);
    g2l16(bP0 + 32, &Bs[1][wave * 32][0]);
    g2l16(bP1 + 32, &Bs[1][wave * 32 + 16][0]);

    for (int it = 0; it < NIT; ++it) {
        const int buf = it % 3;
        if (it > 0) {
            WAIT_VM4();
            RAW_BARRIER();
        }
        if (it + 2 < NIT) {
            const int nb_ = (it + 2) % 3;
            const int ko = (it + 2) * 32;
            g2l16(aP0 + ko, &As[nb_][wave * 32][0]);
            g2l16(aP1 + ko, &As[nb_][wave * 32 + 16][0]);
            g2l16(bP0 + ko, &Bs[nb_][wave * 32][0]);
            g2l16(bP1 + ko, &Bs[nb_][wave * 32 + 16][0]);
        }
        bf16x8 af[4], bfv[4];
        #pragma unroll
        for (int i = 0; i < 4; i++)
            af[i] = *(const bf16x8*)&As[buf][wm * 64 + i * 16 + lrow][kq * 8];
        #pragma unroll
        for (int i = 0; i < 4; i++)
            bfv[i] = *(const bf16x8*)&Bs[buf][wn * 64 + i * 16 + lrow][kq * 8];
        #pragma unroll
        for (int mi = 0; mi < 4; mi++)
            #pragma unroll
            for (int ni = 0; ni < 4; ni++)
                acc[mi][ni] = __builtin_amdgcn_mfma_f32_16x16x32_bf16(
                    af[mi], bfv[ni], acc[mi][ni], 0, 0, 0);
    }

    // epilogue: plain stores into partial buffer P[kc][tok][gn]
    float* Pk = Pbuf + (size_t)kc * T_TOK * DIM;
    const int quad = lane >> 4;
    #pragma unroll
    for (int ni = 0; ni < 4; ni++) {
        int gn = n0 + wn * 64 + ni * 16 + lrow;
        #pragma unroll
        for (int mi = 0; mi < 4; mi++) {
            f32x4 v = acc[mi][ni];
            #pragma unroll
            for (int r = 0; r < 4; r++) {
                int mloc = wm * 64 + mi * 16 + quad * 4 + r;
                if (rbase + mloc < cnt) {
                    Pk[(size_t)s_tok[mloc] * DIM + gn] = v[r];
                }
            }
        }
    }
}

// ================= Fallback path (R2 kernels, used only if ws too small) =================
__global__ __launch_bounds__(256) void k_gather_fb(
    const float* __restrict__ x, const int* __restrict__ sorted,
    unsigned short* __restrict__ Xg)
{
    int g0 = (blockIdx.x * 256 + threadIdx.x) * 8;
    if (g0 >= T_TOK * DIM) return;
    int row = g0 / DIM, col = g0 - row * DIM;
    const float* src = x + (size_t)sorted[row] * DIM + col;
    f32x4 a = *(const f32x4*)(src);
    f32x4 b = *(const f32x4*)(src + 4);
    *(bf16x8*)(Xg + (size_t)row * DIM + col) = pack8(a, b);
}

__global__ __launch_bounds__(256, 3) void k_gemm1_fb(
    const unsigned short* __restrict__ Xg, const float* __restrict__ w1,
    const float* __restrict__ b1, const int* __restrict__ counts,
    const int* __restrict__ offsets, unsigned short* __restrict__ Hbuf)
{
    const int e   = blockIdx.y >> 5;
    const int ti  = blockIdx.y & 31;
    const int cnt = counts[e];
    if (ti * 128 >= cnt) return;
    const int n0    = blockIdx.x * 128;
    const int off   = offsets[e];
    const int rbase = ti * 128;
    const int rmax  = cnt - rbase - 1;
    const int tid   = threadIdx.x;
    const int lane  = tid & 63;
    const int wave  = tid >> 6;
    const int wm = wave >> 1, wn = wave & 1;
    __shared__ unsigned short As[128][72];
    __shared__ unsigned short Bs[128][72];
    const float* w1e = w1 + (size_t)e * DIM * FF;
    f32x4 acc[4][4];
    #pragma unroll
    for (int i = 0; i < 4; i++)
        #pragma unroll
        for (int j = 0; j < 4; j++) acc[i][j] = (f32x4)0.f;
    const int arow = tid >> 1, aseg = tid & 1;
    const int are  = (arow <= rmax) ? arow : 0;
    const unsigned short* abase = Xg + (size_t)(off + rbase + are) * DIM + aseg * 32;
    const int kb = tid >> 5, nb = tid & 31;
    const float* bbase = w1e + (size_t)kb * 8 * FF + n0 + nb * 4;
    bf16x8 aR[4];
    f32x4  bR[8];
    #pragma unroll
    for (int j = 0; j < 4; j++) aR[j] = *(const bf16x8*)(abase + j * 8);
    #pragma unroll
    for (int r = 0; r < 8; r++) bR[r] = *(const f32x4*)(bbase + (size_t)r * FF);
    const int lrow = lane & 15, kq = lane >> 4;
    for (int it = 0; it < DIM / 64; ++it) {
        __syncthreads();
        #pragma unroll
        for (int j = 0; j < 4; j++)
            *(bf16x8*)&As[arow][aseg * 32 + j * 8] = aR[j];
        #pragma unroll
        for (int j = 0; j < 4; j++) {
            bf16x8 c;
            #pragma unroll
            for (int r = 0; r < 8; r++) c[r] = (short)f2bf(bR[r][j]);
            *(bf16x8*)&Bs[nb * 4 + j][kb * 8] = c;
        }
        __syncthreads();
        if (it + 1 < DIM / 64) {
            const unsigned short* an = abase + (it + 1) * 64;
            #pragma unroll
            for (int j = 0; j < 4; j++) aR[j] = *(const bf16x8*)(an + j * 8);
            const float* bn = bbase + (size_t)(it + 1) * 64 * FF;
            #pragma unroll
            for (int r = 0; r < 8; r++) bR[r] = *(const f32x4*)(bn + (size_t)r * FF);
        }
        #pragma unroll
        for (int ks = 0; ks < 2; ks++) {
            bf16x8 af[4], bfr[4];
            #pragma unroll
            for (int i = 0; i < 4; i++)
                af[i] = *(const bf16x8*)&As[wm * 64 + i * 16 + lrow][ks * 32 + kq * 8];
            #pragma unroll
            for (int i = 0; i < 4; i++)
                bfr[i] = *(const bf16x8*)&Bs[wn * 64 + i * 16 + lrow][ks * 32 + kq * 8];
            #pragma unroll
            for (int mi = 0; mi < 4; mi++)
                #pragma unroll
                for (int ni = 0; ni < 4; ni++)
                    acc[mi][ni] = __builtin_amdgcn_mfma_f32_16x16x32_bf16(
                        af[mi], bfr[ni], acc[mi][ni], 0, 0, 0);
        }
    }
    const int quad = lane >> 4;
    #pragma unroll
    for (int ni = 0; ni < 4; ni++) {
        int gn = n0 + wn * 64 + ni * 16 + lrow;
        float bias = b1[e * FF + gn];
        #pragma unroll
        for (int mi = 0; mi < 4; mi++) {
            f32x4 v = acc[mi][ni];
            #pragma unroll
            for (int r = 0; r < 4; r++) {
                int ml = wm * 64 + mi * 16 + quad * 4 + r;
                if (rbase + ml < cnt) {
                    float h = v[r] + bias;
                    h = h > 0.f ? h : 0.f;
                    Hbuf[(size_t)(off + rbase + ml) * FF + gn] = f2bf(h);
                }
            }
        }
    }
}

__global__ __launch_bounds__(256, 4) void k_gemm2_fb(
    const unsigned short* __restrict__ Hbuf, const float* __restrict__ w2,
    const float* __restrict__ b2, const int* __restrict__ sorted,
    const int* __restrict__ counts, const int* __restrict__ offsets,
    const float* __restrict__ probs, float* __restrict__ outh)
{
    const int e   = blockIdx.y >> 5;
    const int ti  = blockIdx.y & 31;
    const int cnt = counts[e];
    if (ti * 128 >= cnt) return;
    const int n0    = blockIdx.x * 64;
    const int off   = offsets[e];
    const int rbase = ti * 128;
    const int rmax  = cnt - rbase - 1;
    const int tid   = threadIdx.x;
    const int lane  = tid & 63;
    const int wave  = tid >> 6;
    const int wm = wave >> 1, wn = wave & 1;
    __shared__ unsigned short As[128][72];
    __shared__ unsigned short Bs[64][72];
    __shared__ int   s_tok[128];
    __shared__ float s_prob[128];
    if (tid < 128) {
        int r = rbase + tid;
        int tk = sorted[off + ((r < cnt) ? r : rbase)];
        s_tok[tid]  = tk;
        s_prob[tid] = probs[tk];
    }
    const float* w2e = w2 + (size_t)e * FF * DIM;
    f32x4 acc[4][2];
    #pragma unroll
    for (int i = 0; i < 4; i++)
        #pragma unroll
        for (int j = 0; j < 2; j++) acc[i][j] = (f32x4)0.f;
    const int arow = tid >> 1, aseg = tid & 1;
    const int are  = (arow <= rmax) ? arow : 0;
    const unsigned short* abase = Hbuf + (size_t)(off + rbase + are) * FF + aseg * 32;
    const int kb = tid >> 5, nb = tid & 31;
    const float* bbase = w2e + (size_t)kb * 8 * DIM + n0 + nb * 2;
    bf16x8 aR[4];
    f32x2  bR[8];
    #pragma unroll
    for (int j = 0; j < 4; j++) aR[j] = *(const bf16x8*)(abase + j * 8);
    #pragma unroll
    for (int r = 0; r < 8; r++) bR[r] = *(const f32x2*)(bbase + (size_t)r * DIM);
    const int lrow = lane & 15, kq = lane >> 4;
    for (int it = 0; it < FF / 64; ++it) {
        __syncthreads();
        #pragma unroll
        for (int j = 0; j < 4; j++)
            *(bf16x8*)&As[arow][aseg * 32 + j * 8] = aR[j];
        {
            bf16x8 c0, c1;
            #pragma unroll
            for (int r = 0; r < 8; r++) { c0[r] = (short)f2bf(bR[r][0]); c1[r] = (short)f2bf(bR[r][1]); }
            *(bf16x8*)&Bs[nb * 2 + 0][kb * 8] = c0;
            *(bf16x8*)&Bs[nb * 2 + 1][kb * 8] = c1;
        }
        __syncthreads();
        if (it + 1 < FF / 64) {
            const unsigned short* an = abase + (it + 1) * 64;
            #pragma unroll
            for (int j = 0; j < 4; j++) aR[j] = *(const bf16x8*)(an + j * 8);
            const float* bn = bbase + (size_t)(it + 1) * 64 * DIM;
            #pragma unroll
            for (int r = 0; r < 8; r++) bR[r] = *(const f32x2*)(bn + (size_t)r * DIM);
        }
        #pragma unroll
        for (int ks = 0; ks < 2; ks++) {
            bf16x8 af[4], bfr[2];
            #pragma unroll
            for (int i = 0; i < 4; i++)
                af[i] = *(const bf16x8*)&As[wm * 64 + i * 16 + lrow][ks * 32 + kq * 8];
            #pragma unroll
            for (int i = 0; i < 2; i++)
                bfr[i] = *(const bf16x8*)&Bs[wn * 32 + i * 16 + lrow][ks * 32 + kq * 8];
            #pragma unroll
            for (int mi = 0; mi < 4; mi++)
                #pragma unroll
                for (int ni = 0; ni < 2; ni++)
                    acc[mi][ni] = __builtin_amdgcn_mfma_f32_16x16x32_bf16(
                        af[mi], bfr[ni], acc[mi][ni], 0, 0, 0);
        }
    }
    const int quad = lane >> 4;
    #pragma unroll
    for (int ni = 0; ni < 2; ni++) {
        int gn = n0 + wn * 32 + ni * 16 + lrow;
        float bias = b2[e * DIM + gn];
        #pragma unroll
        for (int mi = 0; mi < 4; mi++) {
            f32x4 v = acc[mi][ni];
            #pragma unroll
            for (int r = 0; r < 4; r++) {
                int ml = wm * 64 + mi * 16 + quad * 4 + r;
                if (rbase + ml < cnt) {
                    outh[(size_t)s_tok[ml] * DIM + gn] = (v[r] + bias) * s_prob[ml];
                }
            }
        }
    }
}

extern "C" void kernel_launch(void* const* d_in, const int* in_sizes, int n_in,
                              void* d_out, int out_size, void* d_ws, size_t ws_size,
                              hipStream_t stream) {
    (void)in_sizes; (void)n_in; (void)out_size;
    const float* x  = (const float*)d_in[0];
    const float* wr = (const float*)d_in[1];
    const float* w1 = (const float*)d_in[2];
    const float* b1 = (const float*)d_in[3];
    const float* w2 = (const float*)d_in[4];
    const float* b2 = (const float*)d_in[5];

    float* out_hidden = (float*)d_out;                        // [T, D]
    float* out_logits = out_hidden + (size_t)T_TOK * DIM;     // [T, E]
    float* out_eidx   = out_logits + (size_t)T_TOK * NE;      // [T]

    char* ws = (char*)d_ws;
    int*   counts  = (int*)(ws + 0);
    int*   offsets = (int*)(ws + 64);
    float* probs   = (float*)(ws + 128);
    int*   eidx_i  = (int*)(ws + 16512);
    int*   sorted  = (int*)(ws + 32896);
    int*   bucket  = (int*)(ws + 49280);
    unsigned short* Xb   = (unsigned short*)(ws + 180352);    // T*DIM bf16
    unsigned short* Hbuf = (unsigned short*)(ws + 6471808);   // T*FF bf16
    unsigned short* wt1  = (unsigned short*)(ws + 31637632);  // E*FF*DIM bf16 [e][f][d]
    unsigned short* wt2  = (unsigned short*)(ws + 69386368);  // E*DIM*FF bf16 [e][d][f]
    // Pbuf (3 x T x DIM fp32 = 37,748,736 B) ALIASES wt1 exactly: wt1 is dead
    // once gemm1 completes, and gemm2 (writer of Pbuf) is stream-ordered after.
    float* Pbuf = (float*)(ws + 31637632);
    const size_t NEED = 107135104;

    hipMemsetAsync(counts, 0, 32, stream);
    k_router<<<dim3(T_TOK / 4), dim3(256), 0, stream>>>(
        x, wr, out_logits, out_eidx, probs, eidx_i, counts, bucket);
    k_compact<<<dim3(1), dim3(256), 0, stream>>>(counts, offsets, bucket, sorted);

    if (ws_size >= NEED) {
        k_xconv<<<dim3(T_TOK * DIM / 8 / 256), dim3(256), 0, stream>>>(x, Xb);
        k_tconv<<<dim3(FF / 64, DIM / 64, NE), dim3(256), 0, stream>>>(w1, wt1, DIM, FF);
        k_tconv<<<dim3(DIM / 64, FF / 64, NE), dim3(256), 0, stream>>>(w2, wt2, FF, DIM);
        k_gemm1<<<dim3(FF / 128, NE * 32), dim3(256), 0, stream>>>(
            Xb, wt1, b1, sorted, counts, offsets, Hbuf);
        k_gemm2<<<dim3(DIM / 128, NE * 32, 3), dim3(256), 0, stream>>>(
            Hbuf, wt2, sorted, counts, offsets, Pbuf);
        k_fin<<<dim3(T_TOK), dim3(256), 0, stream>>>(
            Pbuf, b2, eidx_i, probs, out_hidden);
    } else {
        k_gather_fb<<<dim3(T_TOK * DIM / 8 / 256), dim3(256), 0, stream>>>(x, sorted, Xb);
        k_gemm1_fb<<<dim3(FF / 128, NE * 32), dim3(256), 0, stream>>>(
            Xb, w1, b1, counts, offsets, Hbuf);
        k_gemm2_fb<<<dim3(DIM / 64, NE * 32), dim3(256), 0, stream>>>(
            Hbuf, w2, b2, sorted, counts, offsets, probs, out_hidden);
    }
}

// Round 6
// 376.605 us; speedup vs baseline: 1.0473x; 1.0079x over previous
//
#include <hip/hip_runtime.h>
#include <hip/hip_bf16.h>

#define T_TOK 4096
#define DIM   768
#define FF    3072
#define NE    8
#define MAXTILES 48

typedef __attribute__((ext_vector_type(8))) short bf16x8;
typedef __attribute__((ext_vector_type(4))) short bf16x4;
typedef __attribute__((ext_vector_type(4))) float f32x4;
typedef __attribute__((ext_vector_type(2))) float f32x2;

typedef __attribute__((address_space(1))) void gvoid_t;
typedef __attribute__((address_space(3))) void lvoid_t;

__device__ __forceinline__ void g2l16(const void* g, void* l) {
    // async global->LDS, 16B per lane; LDS dest must be wave-uniform base
    __builtin_amdgcn_global_load_lds((gvoid_t*)(void*)g, (lvoid_t*)l, 16, 0, 0);
}

// gfx9 waitcnt simm16: vm[3:0] | exp[6:4] | lgkm[11:8] | vm_hi[15:14]
#define WAIT_VM0() __builtin_amdgcn_s_waitcnt(0x0F70)
#define WAIT_VM4() __builtin_amdgcn_s_waitcnt(0x0F74)
#define RAW_BARRIER() asm volatile("s_barrier" ::: "memory")

__device__ __forceinline__ unsigned short f2bf(float f) {
    union { float f; unsigned int u; } v; v.f = f;
    unsigned int u = v.u;
    u += 0x7FFFu + ((u >> 16) & 1u);   // round-to-nearest-even
    return (unsigned short)(u >> 16);
}

__device__ __forceinline__ bf16x8 pack8(f32x4 a, f32x4 b) {
    bf16x8 r;
    r[0] = (short)f2bf(a[0]); r[1] = (short)f2bf(a[1]);
    r[2] = (short)f2bf(a[2]); r[3] = (short)f2bf(a[3]);
    r[4] = (short)f2bf(b[0]); r[5] = (short)f2bf(b[1]);
    r[6] = (short)f2bf(b[2]); r[7] = (short)f2bf(b[3]);
    return r;
}

// ---------------- Router: one wave per token ----------------
__global__ __launch_bounds__(256) void k_router(
    const float* __restrict__ x, const float* __restrict__ wr,
    float* __restrict__ out_logits, float* __restrict__ out_eidx,
    float* __restrict__ probs, int* __restrict__ eidx_i,
    int* __restrict__ counts, int* __restrict__ bucket)
{
    int tok  = (blockIdx.x * 256 + threadIdx.x) >> 6;
    int lane = threadIdx.x & 63;
    if (tok >= T_TOK) return;
    const float* xr = x + (size_t)tok * DIM;
    float acc[NE];
    #pragma unroll
    for (int e = 0; e < NE; e++) acc[e] = 0.f;
    #pragma unroll
    for (int j = 0; j < DIM / 64; j++) {
        int d = j * 64 + lane;
        float xv = xr[d];
        const float* wrow = wr + (size_t)d * NE;
        #pragma unroll
        for (int e = 0; e < NE; e++) acc[e] += xv * wrow[e];
    }
    #pragma unroll
    for (int e = 0; e < NE; e++) {
        #pragma unroll
        for (int off = 32; off >= 1; off >>= 1)
            acc[e] += __shfl_xor(acc[e], off);
    }
    if (lane == 0) {
        float mx = acc[0]; int mi = 0;
        #pragma unroll
        for (int e = 1; e < NE; e++) if (acc[e] > mx) { mx = acc[e]; mi = e; }
        float se = 0.f;
        #pragma unroll
        for (int e = 0; e < NE; e++) se += __expf(acc[e] - mx);
        #pragma unroll
        for (int e = 0; e < NE; e++) out_logits[(size_t)tok * NE + e] = acc[e];
        out_eidx[tok] = (float)mi;
        eidx_i[tok] = mi;
        probs[tok] = 1.f / se;
        int pos = atomicAdd(&counts[mi], 1);
        bucket[mi * T_TOK + pos] = tok;
    }
}

// ---------------- Compact: offsets + sorted list + dense tile table ----------------
// tile_tab aliases bucket[0..MAXTILES) — bucket is dead after the copy loop.
__global__ void k_compact(const int* __restrict__ counts, int* __restrict__ offsets,
                          int* __restrict__ bucket, int* __restrict__ sorted)
{
    __shared__ int soff[NE + 1];
    if (threadIdx.x == 0) {
        int s = 0;
        for (int e = 0; e < NE; e++) { soff[e] = s; s += counts[e]; }
        soff[NE] = s;
        for (int e = 0; e <= NE; e++) offsets[e] = soff[e];
    }
    __syncthreads();
    for (int e = 0; e < NE; e++) {
        int c = counts[e], o = soff[e];
        for (int i = threadIdx.x; i < c; i += blockDim.x)
            sorted[o + i] = bucket[e * T_TOK + i];
    }
    __syncthreads();   // all bucket reads complete before tile_tab overwrite
    if (threadIdx.x == 0) {
        int nt = 0;
        for (int e = 0; e < NE; e++) {
            int c = counts[e];
            for (int t = 0; t * 128 < c && nt < MAXTILES; t++)
                bucket[nt++] = (e << 8) | t;      // tile_tab entry
        }
        for (int i = nt; i < MAXTILES; i++) bucket[i] = -1;
    }
}

// ---------------- x -> bf16 (unsorted) ----------------
__global__ __launch_bounds__(256) void k_xconv(
    const float* __restrict__ x, unsigned short* __restrict__ Xb)
{
    int g0 = (blockIdx.x * 256 + threadIdx.x) * 8;
    if (g0 >= T_TOK * DIM) return;
    f32x4 a = *(const f32x4*)(x + g0);
    f32x4 b = *(const f32x4*)(x + g0 + 4);
    *(bf16x8*)(Xb + g0) = pack8(a, b);
}

// ---------------- transpose+convert: in[R][C] f32 -> out[C][R] bf16, per expert ----------------
__global__ __launch_bounds__(256) void k_tconv(
    const float* __restrict__ in, unsigned short* __restrict__ out, int R, int C)
{
    const size_t es = (size_t)R * C;
    in  += blockIdx.z * es;
    out += blockIdx.z * es;
    const int c0 = blockIdx.x * 64, r0 = blockIdx.y * 64;
    __shared__ unsigned short t[64][72];
    const int tr = threadIdx.x >> 2, tc = (threadIdx.x & 3) * 16;
    const float* src = in + (size_t)(r0 + tr) * C + c0 + tc;
    f32x4 v0 = *(const f32x4*)(src);
    f32x4 v1 = *(const f32x4*)(src + 4);
    f32x4 v2 = *(const f32x4*)(src + 8);
    f32x4 v3 = *(const f32x4*)(src + 12);
    const int xb = (tc >> 4) & 3;
    const int pr = (((tr >> 3) ^ xb) & 7) * 8 + (tr & 7);   // swizzled r-slot
    #pragma unroll
    for (int j = 0; j < 4; j++) {
        t[tc + j][pr]      = f2bf(v0[j]);
        t[tc + 4 + j][pr]  = f2bf(v1[j]);
        t[tc + 8 + j][pr]  = f2bf(v2[j]);
        t[tc + 12 + j][pr] = f2bf(v3[j]);
    }
    __syncthreads();
    const int oc = threadIdx.x >> 2, orr = (threadIdx.x & 3) * 16;
    const int rx = (oc >> 4) & 3;
    const int p0 = ((((orr >> 3) + 0) ^ rx) & 7) * 8;
    const int p1 = ((((orr >> 3) + 1) ^ rx) & 7) * 8;
    bf16x8 o0 = *(const bf16x8*)&t[oc][p0];
    bf16x8 o1 = *(const bf16x8*)&t[oc][p1];
    unsigned short* dst = out + (size_t)(c0 + oc) * R + r0 + orr;
    *(bf16x8*)(dst)     = o0;
    *(bf16x8*)(dst + 8) = o1;
}

// ---------------- fin: out = prob * (P0+P1+P2 + b2[e]) ----------------
__global__ __launch_bounds__(256) void k_fin(
    const float* __restrict__ P, const float* __restrict__ b2,
    const int* __restrict__ eidx, const float* __restrict__ probs,
    float* __restrict__ outh)
{
    const int tok = blockIdx.x;
    const float p = probs[tok];
    const int e = eidx[tok];
    const float* p0 = P + (size_t)tok * DIM;
    const float* p1 = p0 + (size_t)T_TOK * DIM;
    const float* p2 = p1 + (size_t)T_TOK * DIM;
    const float* br = b2 + e * DIM;
    float* o = outh + (size_t)tok * DIM;
    for (int d = threadIdx.x; d < DIM; d += 256)
        o[d] = p * (p0[d] + p1[d] + p2[d] + br[d]);
}

// ---------------- GEMM1: H = relu(X[sorted] @ w1t[e]^T + b1), 128x128, BK=32, 3-buf depth-2 ----------------
__global__ __launch_bounds__(256, 3) void k_gemm1(
    const unsigned short* __restrict__ Xb, const unsigned short* __restrict__ wt1,
    const float* __restrict__ b1, const int* __restrict__ sorted,
    const int* __restrict__ counts, const int* __restrict__ offsets,
    const int* __restrict__ tile_tab, unsigned short* __restrict__ Hbuf)
{
    const int tv = tile_tab[blockIdx.y];
    if (tv < 0) return;
    const int e  = tv >> 8;
    const int ti = tv & 255;
    const int cnt = counts[e];
    const int n0 = blockIdx.x * 128;
    const int off = offsets[e];
    const int rbase = ti * 128;
    const int tid = threadIdx.x, lane = tid & 63, wave = tid >> 6;
    const int wm = wave >> 1, wn = wave & 1;

    __shared__ unsigned short As[3][128][32];
    __shared__ unsigned short Bs[3][128][32];

    const int lr = lane >> 2;
    const int ls = (lane & 3) * 8;

    int r0 = rbase + wave * 32 + lr;        if (r0 >= cnt) r0 = rbase;
    int r1 = rbase + wave * 32 + 16 + lr;   if (r1 >= cnt) r1 = rbase;
    const unsigned short* aP0 = Xb + (size_t)sorted[off + r0] * DIM + ls;   // fused gather
    const unsigned short* aP1 = Xb + (size_t)sorted[off + r1] * DIM + ls;
    const unsigned short* wB  = wt1 + (size_t)e * FF * DIM;                 // [FF][DIM]
    const unsigned short* bP0 = wB + (size_t)(n0 + wave * 32 + lr) * DIM + ls;
    const unsigned short* bP1 = wB + (size_t)(n0 + wave * 32 + 16 + lr) * DIM + ls;

    f32x4 acc[4][4];
    #pragma unroll
    for (int i = 0; i < 4; i++)
        #pragma unroll
        for (int j = 0; j < 4; j++) acc[i][j] = (f32x4)0.f;

    const int lrow = lane & 15, kq = lane >> 4;
    const int NIT = DIM / 32;   // 24

    // prologue: tile0; drain; tile1
    g2l16(aP0, &As[0][wave * 32][0]);
    g2l16(aP1, &As[0][wave * 32 + 16][0]);
    g2l16(bP0, &Bs[0][wave * 32][0]);
    g2l16(bP1, &Bs[0][wave * 32 + 16][0]);
    __syncthreads();
    g2l16(aP0 + 32, &As[1][wave * 32][0]);
    g2l16(aP1 + 32, &As[1][wave * 32 + 16][0]);
    g2l16(bP0 + 32, &Bs[1][wave * 32][0]);
    g2l16(bP1 + 32, &Bs[1][wave * 32 + 16][0]);

    for (int it = 0; it < NIT; ++it) {
        const int buf = it % 3;
        if (it > 0) {
            WAIT_VM4();       // oldest tile (it) done; tile it+1 stays in flight
            RAW_BARRIER();
        }
        if (it + 2 < NIT) {
            const int nb_ = (it + 2) % 3;
            const int ko = (it + 2) * 32;
            g2l16(aP0 + ko, &As[nb_][wave * 32][0]);
            g2l16(aP1 + ko, &As[nb_][wave * 32 + 16][0]);
            g2l16(bP0 + ko, &Bs[nb_][wave * 32][0]);
            g2l16(bP1 + ko, &Bs[nb_][wave * 32 + 16][0]);
        }
        bf16x8 af[4], bfv[4];
        #pragma unroll
        for (int i = 0; i < 4; i++)
            af[i] = *(const bf16x8*)&As[buf][wm * 64 + i * 16 + lrow][kq * 8];
        #pragma unroll
        for (int i = 0; i < 4; i++)
            bfv[i] = *(const bf16x8*)&Bs[buf][wn * 64 + i * 16 + lrow][kq * 8];
        #pragma unroll
        for (int mi = 0; mi < 4; mi++)
            #pragma unroll
            for (int ni = 0; ni < 4; ni++)
                acc[mi][ni] = __builtin_amdgcn_mfma_f32_16x16x32_bf16(
                    af[mi], bfv[ni], acc[mi][ni], 0, 0, 0);
    }

    const int quad = lane >> 4;
    #pragma unroll
    for (int ni = 0; ni < 4; ni++) {
        int gn = n0 + wn * 64 + ni * 16 + lrow;
        float bias = b1[e * FF + gn];
        #pragma unroll
        for (int mi = 0; mi < 4; mi++) {
            f32x4 v = acc[mi][ni];
            #pragma unroll
            for (int r = 0; r < 4; r++) {
                int ml = rbase + wm * 64 + mi * 16 + quad * 4 + r;
                if (ml < cnt) {
                    float h = v[r] + bias; h = h > 0.f ? h : 0.f;
                    Hbuf[(size_t)(off + ml) * FF + gn] = f2bf(h);
                }
            }
        }
    }
}

// ---------------- GEMM2: P[kc] = H @ w2t[e]^T chunk, 128x128, split-K x3, plain stores ----------------
__global__ __launch_bounds__(256, 3) void k_gemm2(
    const unsigned short* __restrict__ Hbuf, const unsigned short* __restrict__ wt2,
    const int* __restrict__ sorted, const int* __restrict__ counts,
    const int* __restrict__ offsets, const int* __restrict__ tile_tab,
    float* __restrict__ Pbuf)
{
    const int tv = tile_tab[blockIdx.y];
    if (tv < 0) return;
    const int e  = tv >> 8;
    const int ti = tv & 255;
    const int cnt = counts[e];
    const int n0 = blockIdx.x * 128;          // N=768 -> 6 tiles
    const int kc = blockIdx.z;                // 3 chunks of K=1024
    const int off = offsets[e];
    const int rbase = ti * 128;
    const int tid = threadIdx.x, lane = tid & 63, wave = tid >> 6;
    const int wm = wave >> 1, wn = wave & 1;

    __shared__ unsigned short As[3][128][32];
    __shared__ unsigned short Bs[3][128][32];
    __shared__ int s_tok[128];

    if (tid < 128) {
        int rr = rbase + tid; if (rr >= cnt) rr = rbase;
        s_tok[tid] = sorted[off + rr];
    }

    const int lr = lane >> 2, ls = (lane & 3) * 8;
    int r0 = rbase + wave * 32 + lr;        if (r0 >= cnt) r0 = rbase;
    int r1 = rbase + wave * 32 + 16 + lr;   if (r1 >= cnt) r1 = rbase;
    const unsigned short* aP0 = Hbuf + (size_t)(off + r0) * FF + kc * 1024 + ls;
    const unsigned short* aP1 = Hbuf + (size_t)(off + r1) * FF + kc * 1024 + ls;
    const unsigned short* wB  = wt2 + (size_t)e * DIM * FF;                 // [DIM][FF]
    const unsigned short* bP0 = wB + (size_t)(n0 + wave * 32 + lr) * FF + kc * 1024 + ls;
    const unsigned short* bP1 = wB + (size_t)(n0 + wave * 32 + 16 + lr) * FF + kc * 1024 + ls;

    f32x4 acc[4][4];
    #pragma unroll
    for (int i = 0; i < 4; i++)
        #pragma unroll
        for (int j = 0; j < 4; j++) acc[i][j] = (f32x4)0.f;

    const int lrow = lane & 15, kq = lane >> 4;
    const int NIT = 1024 / 32;   // 32

    g2l16(aP0, &As[0][wave * 32][0]);
    g2l16(aP1, &As[0][wave * 32 + 16][0]);
    g2l16(bP0, &Bs[0][wave * 32][0]);
    g2l16(bP1, &Bs[0][wave * 32 + 16][0]);
    __syncthreads();                          // also fences s_tok
    g2l16(aP0 + 32, &As[1][wave * 32][0]);
    g2l16(aP1 + 32, &As[1][wave * 32 + 16][0]);
    g2l16(bP0 + 32, &Bs[1][wave * 32][0]);
    g2l16(bP1 + 32, &Bs[1][wave * 32 + 16][0]);

    for (int it = 0; it < NIT; ++it) {
        const int buf = it % 3;
        if (it > 0) {
            WAIT_VM4();
            RAW_BARRIER();
        }
        if (it + 2 < NIT) {
            const int nb_ = (it + 2) % 3;
            const int ko = (it + 2) * 32;
            g2l16(aP0 + ko, &As[nb_][wave * 32][0]);
            g2l16(aP1 + ko, &As[nb_][wave * 32 + 16][0]);
            g2l16(bP0 + ko, &Bs[nb_][wave * 32][0]);
            g2l16(bP1 + ko, &Bs[nb_][wave * 32 + 16][0]);
        }
        bf16x8 af[4], bfv[4];
        #pragma unroll
        for (int i = 0; i < 4; i++)
            af[i] = *(const bf16x8*)&As[buf][wm * 64 + i * 16 + lrow][kq * 8];
        #pragma unroll
        for (int i = 0; i < 4; i++)
            bfv[i] = *(const bf16x8*)&Bs[buf][wn * 64 + i * 16 + lrow][kq * 8];
        #pragma unroll
        for (int mi = 0; mi < 4; mi++)
            #pragma unroll
            for (int ni = 0; ni < 4; ni++)
                acc[mi][ni] = __builtin_amdgcn_mfma_f32_16x16x32_bf16(
                    af[mi], bfv[ni], acc[mi][ni], 0, 0, 0);
    }

    // epilogue: plain stores into partial buffer P[kc][tok][gn]
    float* Pk = Pbuf + (size_t)kc * T_TOK * DIM;
    const int quad = lane >> 4;
    #pragma unroll
    for (int ni = 0; ni < 4; ni++) {
        int gn = n0 + wn * 64 + ni * 16 + lrow;
        #pragma unroll
        for (int mi = 0; mi < 4; mi++) {
            f32x4 v = acc[mi][ni];
            #pragma unroll
            for (int r = 0; r < 4; r++) {
                int mloc = wm * 64 + mi * 16 + quad * 4 + r;
                if (rbase + mloc < cnt) {
                    Pk[(size_t)s_tok[mloc] * DIM + gn] = v[r];
                }
            }
        }
    }
}

// ================= Fallback path (R2 kernels, used only if ws too small) =================
__global__ __launch_bounds__(256) void k_gather_fb(
    const float* __restrict__ x, const int* __restrict__ sorted,
    unsigned short* __restrict__ Xg)
{
    int g0 = (blockIdx.x * 256 + threadIdx.x) * 8;
    if (g0 >= T_TOK * DIM) return;
    int row = g0 / DIM, col = g0 - row * DIM;
    const float* src = x + (size_t)sorted[row] * DIM + col;
    f32x4 a = *(const f32x4*)(src);
    f32x4 b = *(const f32x4*)(src + 4);
    *(bf16x8*)(Xg + (size_t)row * DIM + col) = pack8(a, b);
}

__global__ __launch_bounds__(256, 3) void k_gemm1_fb(
    const unsigned short* __restrict__ Xg, const float* __restrict__ w1,
    const float* __restrict__ b1, const int* __restrict__ counts,
    const int* __restrict__ offsets, unsigned short* __restrict__ Hbuf)
{
    const int e   = blockIdx.y >> 5;
    const int ti  = blockIdx.y & 31;
    const int cnt = counts[e];
    if (ti * 128 >= cnt) return;
    const int n0    = blockIdx.x * 128;
    const int off   = offsets[e];
    const int rbase = ti * 128;
    const int rmax  = cnt - rbase - 1;
    const int tid   = threadIdx.x;
    const int lane  = tid & 63;
    const int wave  = tid >> 6;
    const int wm = wave >> 1, wn = wave & 1;
    __shared__ unsigned short As[128][72];
    __shared__ unsigned short Bs[128][72];
    const float* w1e = w1 + (size_t)e * DIM * FF;
    f32x4 acc[4][4];
    #pragma unroll
    for (int i = 0; i < 4; i++)
        #pragma unroll
        for (int j = 0; j < 4; j++) acc[i][j] = (f32x4)0.f;
    const int arow = tid >> 1, aseg = tid & 1;
    const int are  = (arow <= rmax) ? arow : 0;
    const unsigned short* abase = Xg + (size_t)(off + rbase + are) * DIM + aseg * 32;
    const int kb = tid >> 5, nb = tid & 31;
    const float* bbase = w1e + (size_t)kb * 8 * FF + n0 + nb * 4;
    bf16x8 aR[4];
    f32x4  bR[8];
    #pragma unroll
    for (int j = 0; j < 4; j++) aR[j] = *(const bf16x8*)(abase + j * 8);
    #pragma unroll
    for (int r = 0; r < 8; r++) bR[r] = *(const f32x4*)(bbase + (size_t)r * FF);
    const int lrow = lane & 15, kq = lane >> 4;
    for (int it = 0; it < DIM / 64; ++it) {
        __syncthreads();
        #pragma unroll
        for (int j = 0; j < 4; j++)
            *(bf16x8*)&As[arow][aseg * 32 + j * 8] = aR[j];
        #pragma unroll
        for (int j = 0; j < 4; j++) {
            bf16x8 c;
            #pragma unroll
            for (int r = 0; r < 8; r++) c[r] = (short)f2bf(bR[r][j]);
            *(bf16x8*)&Bs[nb * 4 + j][kb * 8] = c;
        }
        __syncthreads();
        if (it + 1 < DIM / 64) {
            const unsigned short* an = abase + (it + 1) * 64;
            #pragma unroll
            for (int j = 0; j < 4; j++) aR[j] = *(const bf16x8*)(an + j * 8);
            const float* bn = bbase + (size_t)(it + 1) * 64 * FF;
            #pragma unroll
            for (int r = 0; r < 8; r++) bR[r] = *(const f32x4*)(bn + (size_t)r * FF);
        }
        #pragma unroll
        for (int ks = 0; ks < 2; ks++) {
            bf16x8 af[4], bfr[4];
            #pragma unroll
            for (int i = 0; i < 4; i++)
                af[i] = *(const bf16x8*)&As[wm * 64 + i * 16 + lrow][ks * 32 + kq * 8];
            #pragma unroll
            for (int i = 0; i < 4; i++)
                bfr[i] = *(const bf16x8*)&Bs[wn * 64 + i * 16 + lrow][ks * 32 + kq * 8];
            #pragma unroll
            for (int mi = 0; mi < 4; mi++)
                #pragma unroll
                for (int ni = 0; ni < 4; ni++)
                    acc[mi][ni] = __builtin_amdgcn_mfma_f32_16x16x32_bf16(
                        af[mi], bfr[ni], acc[mi][ni], 0, 0, 0);
        }
    }
    const int quad = lane >> 4;
    #pragma unroll
    for (int ni = 0; ni < 4; ni++) {
        int gn = n0 + wn * 64 + ni * 16 + lrow;
        float bias = b1[e * FF + gn];
        #pragma unroll
        for (int mi = 0; mi < 4; mi++) {
            f32x4 v = acc[mi][ni];
            #pragma unroll
            for (int r = 0; r < 4; r++) {
                int ml = wm * 64 + mi * 16 + quad * 4 + r;
                if (rbase + ml < cnt) {
                    float h = v[r] + bias;
                    h = h > 0.f ? h : 0.f;
                    Hbuf[(size_t)(off + rbase + ml) * FF + gn] = f2bf(h);
                }
            }
        }
    }
}

__global__ __launch_bounds__(256, 4) void k_gemm2_fb(
    const unsigned short* __restrict__ Hbuf, const float* __restrict__ w2,
    const float* __restrict__ b2, const int* __restrict__ sorted,
    const int* __restrict__ counts, const int* __restrict__ offsets,
    const float* __restrict__ probs, float* __restrict__ outh)
{
    const int e   = blockIdx.y >> 5;
    const int ti  = blockIdx.y & 31;
    const int cnt = counts[e];
    if (ti * 128 >= cnt) return;
    const int n0    = blockIdx.x * 64;
    const int off   = offsets[e];
    const int rbase = ti * 128;
    const int rmax  = cnt - rbase - 1;
    const int tid   = threadIdx.x;
    const int lane  = tid & 63;
    const int wave  = tid >> 6;
    const int wm = wave >> 1, wn = wave & 1;
    __shared__ unsigned short As[128][72];
    __shared__ unsigned short Bs[64][72];
    __shared__ int   s_tok[128];
    __shared__ float s_prob[128];
    if (tid < 128) {
        int r = rbase + tid;
        int tk = sorted[off + ((r < cnt) ? r : rbase)];
        s_tok[tid]  = tk;
        s_prob[tid] = probs[tk];
    }
    const float* w2e = w2 + (size_t)e * FF * DIM;
    f32x4 acc[4][2];
    #pragma unroll
    for (int i = 0; i < 4; i++)
        #pragma unroll
        for (int j = 0; j < 2; j++) acc[i][j] = (f32x4)0.f;
    const int arow = tid >> 1, aseg = tid & 1;
    const int are  = (arow <= rmax) ? arow : 0;
    const unsigned short* abase = Hbuf + (size_t)(off + rbase + are) * FF + aseg * 32;
    const int kb = tid >> 5, nb = tid & 31;
    const float* bbase = w2e + (size_t)kb * 8 * DIM + n0 + nb * 2;
    bf16x8 aR[4];
    f32x2  bR[8];
    #pragma unroll
    for (int j = 0; j < 4; j++) aR[j] = *(const bf16x8*)(abase + j * 8);
    #pragma unroll
    for (int r = 0; r < 8; r++) bR[r] = *(const f32x2*)(bbase + (size_t)r * DIM);
    const int lrow = lane & 15, kq = lane >> 4;
    for (int it = 0; it < FF / 64; ++it) {
        __syncthreads();
        #pragma unroll
        for (int j = 0; j < 4; j++)
            *(bf16x8*)&As[arow][aseg * 32 + j * 8] = aR[j];
        {
            bf16x8 c0, c1;
            #pragma unroll
            for (int r = 0; r < 8; r++) { c0[r] = (short)f2bf(bR[r][0]); c1[r] = (short)f2bf(bR[r][1]); }
            *(bf16x8*)&Bs[nb * 2 + 0][kb * 8] = c0;
            *(bf16x8*)&Bs[nb * 2 + 1][kb * 8] = c1;
        }
        __syncthreads();
        if (it + 1 < FF / 64) {
            const unsigned short* an = abase + (it + 1) * 64;
            #pragma unroll
            for (int j = 0; j < 4; j++) aR[j] = *(const bf16x8*)(an + j * 8);
            const float* bn = bbase + (size_t)(it + 1) * 64 * DIM;
            #pragma unroll
            for (int r = 0; r < 8; r++) bR[r] = *(const f32x2*)(bn + (size_t)r * DIM);
        }
        #pragma unroll
        for (int ks = 0; ks < 2; ks++) {
            bf16x8 af[4], bfr[2];
            #pragma unroll
            for (int i = 0; i < 4; i++)
                af[i] = *(const bf16x8*)&As[wm * 64 + i * 16 + lrow][ks * 32 + kq * 8];
            #pragma unroll
            for (int i = 0; i < 2; i++)
                bfr[i] = *(const bf16x8*)&Bs[wn * 32 + i * 16 + lrow][ks * 32 + kq * 8];
            #pragma unroll
            for (int mi = 0; mi < 4; mi++)
                #pragma unroll
                for (int ni = 0; ni < 2; ni++)
                    acc[mi][ni] = __builtin_amdgcn_mfma_f32_16x16x32_bf16(
                        af[mi], bfr[ni], acc[mi][ni], 0, 0, 0);
        }
    }
    const int quad = lane >> 4;
    #pragma unroll
    for (int ni = 0; ni < 2; ni++) {
        int gn = n0 + wn * 32 + ni * 16 + lrow;
        float bias = b2[e * DIM + gn];
        #pragma unroll
        for (int mi = 0; mi < 4; mi++) {
            f32x4 v = acc[mi][ni];
            #pragma unroll
            for (int r = 0; r < 4; r++) {
                int ml = wm * 64 + mi * 16 + quad * 4 + r;
                if (rbase + ml < cnt) {
                    outh[(size_t)s_tok[ml] * DIM + gn] = (v[r] + bias) * s_prob[ml];
                }
            }
        }
    }
}

extern "C" void kernel_launch(void* const* d_in, const int* in_sizes, int n_in,
                              void* d_out, int out_size, void* d_ws, size_t ws_size,
                              hipStream_t stream) {
    (void)in_sizes; (void)n_in; (void)out_size;
    const float* x  = (const float*)d_in[0];
    const float* wr = (const float*)d_in[1];
    const float* w1 = (const float*)d_in[2];
    const float* b1 = (const float*)d_in[3];
    const float* w2 = (const float*)d_in[4];
    const float* b2 = (const float*)d_in[5];

    float* out_hidden = (float*)d_out;                        // [T, D]
    float* out_logits = out_hidden + (size_t)T_TOK * DIM;     // [T, E]
    float* out_eidx   = out_logits + (size_t)T_TOK * NE;      // [T]

    char* ws = (char*)d_ws;
    int*   counts  = (int*)(ws + 0);
    int*   offsets = (int*)(ws + 64);
    float* probs   = (float*)(ws + 128);
    int*   eidx_i  = (int*)(ws + 16512);
    int*   sorted  = (int*)(ws + 32896);
    int*   bucket  = (int*)(ws + 49280);
    int*   tile_tab = bucket;                                 // aliases bucket[0..48) after k_compact
    unsigned short* Xb   = (unsigned short*)(ws + 180352);    // T*DIM bf16
    unsigned short* Hbuf = (unsigned short*)(ws + 6471808);   // T*FF bf16
    unsigned short* wt1  = (unsigned short*)(ws + 31637632);  // E*FF*DIM bf16 [e][f][d]
    unsigned short* wt2  = (unsigned short*)(ws + 69386368);  // E*DIM*FF bf16 [e][d][f]
    // Pbuf (3 x T x DIM fp32 = 37,748,736 B) ALIASES wt1: wt1 dead after gemm1.
    float* Pbuf = (float*)(ws + 31637632);
    const size_t NEED = 107135104;

    hipMemsetAsync(counts, 0, 32, stream);
    k_router<<<dim3(T_TOK / 4), dim3(256), 0, stream>>>(
        x, wr, out_logits, out_eidx, probs, eidx_i, counts, bucket);
    k_compact<<<dim3(1), dim3(256), 0, stream>>>(counts, offsets, bucket, sorted);

    if (ws_size >= NEED) {
        k_xconv<<<dim3(T_TOK * DIM / 8 / 256), dim3(256), 0, stream>>>(x, Xb);
        k_tconv<<<dim3(FF / 64, DIM / 64, NE), dim3(256), 0, stream>>>(w1, wt1, DIM, FF);
        k_tconv<<<dim3(DIM / 64, FF / 64, NE), dim3(256), 0, stream>>>(w2, wt2, FF, DIM);
        k_gemm1<<<dim3(FF / 128, MAXTILES), dim3(256), 0, stream>>>(
            Xb, wt1, b1, sorted, counts, offsets, tile_tab, Hbuf);
        k_gemm2<<<dim3(DIM / 128, MAXTILES, 3), dim3(256), 0, stream>>>(
            Hbuf, wt2, sorted, counts, offsets, tile_tab, Pbuf);
        k_fin<<<dim3(T_TOK), dim3(256), 0, stream>>>(
            Pbuf, b2, eidx_i, probs, out_hidden);
    } else {
        k_gather_fb<<<dim3(T_TOK * DIM / 8 / 256), dim3(256), 0, stream>>>(x, sorted, Xb);
        k_gemm1_fb<<<dim3(FF / 128, NE * 32), dim3(256), 0, stream>>>(
            Xb, w1, b1, counts, offsets, Hbuf);
        k_gemm2_fb<<<dim3(DIM / 64, NE * 32), dim3(256), 0, stream>>>(
            Hbuf, w2, b2, sorted, counts, offsets, probs, out_hidden);
    }
}